// Round 9
// baseline (209.361 us; speedup 1.0000x reference)
//
#include <hip/hip_runtime.h>
#include <math.h>

#define BATCH 262144
#define N 8
#define BLK 64
#define NBLK (BATCH / BLK)   // 4096 single-wave blocks = 16/CU, one generation
#define NCMP 28

typedef float v2f __attribute__((ext_vector_type(2)));

// ---- forced VOP3P dual-FP32 (LLVM often scalarizes <2 x float>; don't let it) ----
__device__ __forceinline__ v2f pk_fma(v2f a, v2f b, v2f c) {          // a*b + c
    v2f d; asm("v_pk_fma_f32 %0, %1, %2, %3" : "=v"(d) : "v"(a), "v"(b), "v"(c)); return d;
}
__device__ __forceinline__ v2f pk_fma_na(v2f a, v2f b, v2f c) {       // -a*b + c
    v2f d; asm("v_pk_fma_f32 %0, %1, %2, %3 neg_lo:[1,0,0] neg_hi:[1,0,0]"
               : "=v"(d) : "v"(a), "v"(b), "v"(c)); return d;
}
__device__ __forceinline__ v2f pk_sub(v2f a, v2f b) {                 // a - b
    v2f d; asm("v_pk_add_f32 %0, %1, %2 neg_lo:[0,1] neg_hi:[0,1]"
               : "=v"(d) : "v"(a), "v"(b)); return d;
}
__device__ __forceinline__ v2f pk_mul(v2f a, v2f b) {
    v2f d; asm("v_pk_mul_f32 %0, %1, %2" : "=v"(d) : "v"(a), "v"(b)); return d;
}

// comparator schedule + per-row-pair support masks (cols possibly nonzero
// BEFORE comparator k; pruning/half-blends are exact, not approximations)
struct Net { int a[NCMP]; unsigned sup2[N / 2][NCMP]; };
constexpr Net make_net() {
    Net n{};
    int k = 0;
    for (int L = 0; L < N; ++L)
        for (int a = (L & 1); a < N - 1; a += 2)
            n.a[k++] = a;
    for (int r = 0; r < N / 2; ++r) {
        unsigned s = (1u << (2 * r)) | (1u << (2 * r + 1));
        for (int q = 0; q < NCMP; ++q) {
            n.sup2[r][q] = s;
            unsigned m = 3u << n.a[q];
            if (s & m) s |= m;
        }
    }
    return n;
}
constexpr Net NET = make_net();

// alpha(z) = 0.5 + atan(z)/pi. Deg-5 minimax atan on [0,1], rcp arg-reduce.
__device__ __forceinline__ float cauchy_alpha(float z10) {
    float az  = __builtin_fabsf(z10);
    bool  big = az > 1.0f;
    float inv = __builtin_amdgcn_rcpf(az);
    float t   = big ? inv : az;
    float t2  = t * t;
    float p   = 0.1417796f;
    p = __builtin_fmaf(p, t2, -0.3258092f);
    p = __builtin_fmaf(p, t2, 0.9992150f);
    float at = p * t;
    float r  = big ? (1.5707963267948966f - at) : at;
    float sr = __builtin_copysignf(r, z10);
    return __builtin_fmaf(sr, 0.31830988618379067f, 0.5f);
}

__global__ __launch_bounds__(BLK, 4) void diffsort_loss_kernel(
    const float* __restrict__ pred,
    const float* __restrict__ labels,
    const float* __restrict__ rank_ema,
    float* __restrict__ partial,
    unsigned int* __restrict__ counter,   // zeroed by hipMemsetAsync pre-launch
    float* __restrict__ out)
{
    const int tid = threadIdx.x;
    const int row = blockIdx.x * BLK + tid;

    __shared__ float ema[N];
    if (tid < N) ema[tid] = rank_ema[tid];
    __syncthreads();

    const float4* lp = (const float4*)(labels + (size_t)row * N);
    const float4* pp = (const float4*)(pred   + (size_t)row * N);
    float4 l0 = lp[0], l1 = lp[1];
    float4 p0 = pp[0], p1 = pp[1];
    float lab[N] = {l0.x, l0.y, l0.z, l0.w, l1.x, l1.y, l1.z, l1.w};
    float prd[N] = {p0.x, p0.y, p0.z, p0.w, p1.x, p1.y, p1.z, p1.w};

    // ---- rank_true (stable argsort of -labels) ----
    int rt[N];
#pragma unroll
    for (int i = 0; i < N; ++i) rt[i] = 0;
#pragma unroll
    for (int i = 0; i < N; ++i)
#pragma unroll
        for (int j = i + 1; j < N; ++j) {
            unsigned c = lab[j] > lab[i];
            rt[i] += c;
            rt[j] += 1u - c;
        }

    // ---- x = rank_ema[rt] - pred ----
    float x[N];
#pragma unroll
    for (int i = 0; i < N; ++i)
        x[i] = ema[rt[i]] - prd[i];

    // ---- P as packed row-pairs, init identity ----
    v2f p2[N / 2][N];
#pragma unroll
    for (int r = 0; r < N / 2; ++r)
#pragma unroll
        for (int j = 0; j < N; ++j) {
            v2f v;
            v.x = (j == 2 * r)     ? 1.0f : 0.0f;
            v.y = (j == 2 * r + 1) ? 1.0f : 0.0f;
            p2[r][j] = v;
        }

    // ---- odd-even network; P-blends in forced v_pk_* (2x work/slot) ----
#pragma unroll
    for (int k = 0; k < NCMP; ++k) {
        const int ia = NET.a[k], ib = ia + 1;
        const float a = x[ia], b = x[ib];
        const float z = b - a;
        const float alpha = cauchy_alpha(10.0f * z);
        x[ia] = __builtin_fmaf(-alpha, z, b);
        x[ib] = __builtin_fmaf( alpha, z, a);
        v2f al2; al2.x = alpha; al2.y = alpha;
#pragma unroll
        for (int r = 0; r < N / 2; ++r) {
            const bool la = (NET.sup2[r][k] >> ia) & 1u;   // compile-time
            const bool lb = (NET.sup2[r][k] >> ib) & 1u;   // compile-time
            if (la && lb) {                 // full blend: 3 pk-slots
                const v2f ca = p2[r][ia], cb = p2[r][ib];
                const v2f d  = pk_sub(ca, cb);
                p2[r][ia] = pk_fma(al2, d, cb);
                p2[r][ib] = pk_fma_na(al2, d, ca);
            } else if (la) {                // cb == 0: 2 pk-slots
                const v2f ca = p2[r][ia];
                p2[r][ia] = pk_mul(al2, ca);
                p2[r][ib] = pk_fma_na(al2, ca, ca);
            } else if (lb) {                // ca == 0: 2 pk-slots
                const v2f cb = p2[r][ib];
                p2[r][ia] = pk_fma_na(al2, cb, cb);
                p2[r][ib] = pk_mul(al2, cb);
            } // both zero: skip
        }
    }

    // ---- loss: gt row i one-hot at col rt[i]; one log per P-row ----
    float s = 0.0f;
#pragma unroll
    for (int r = 0; r < N / 2; ++r) {
        const int h0 = rt[2 * r], h1 = rt[2 * r + 1];
        v2f arg; arg.x = 1.0f; arg.y = 1.0f;
#pragma unroll
        for (int j = 0; j < N; ++j) {
            const v2f pv = p2[r][j];
            v2f f;
            f.x = (h0 == j) ? pv.x : (1.0f - pv.x);
            f.y = (h1 == j) ? pv.y : (1.0f - pv.y);
            arg = pk_mul(arg, f);
        }
        s += __logf(fmaxf(arg.x, 1e-37f));
        s += __logf(fmaxf(arg.y, 1e-37f));
    }

    // ---- wave(64) reduce -> partial; last-done block folds all partials ----
#pragma unroll
    for (int off = 32; off > 0; off >>= 1)
        s += __shfl_down(s, off);
    if (tid == 0) partial[blockIdx.x] = s;

    __threadfence();                       // release partial before counting
    int last = 0;
    if (tid == 0)
        last = (atomicAdd(counter, 1u) == (unsigned)(NBLK - 1));
    last = __shfl(last, 0);
    if (last) {
        __threadfence();                   // acquire others' partials
        float t = 0.0f;
#pragma unroll
        for (int k = 0; k < NBLK / BLK; ++k)
            t += partial[tid + k * BLK];   // coalesced per iteration
#pragma unroll
        for (int off = 32; off > 0; off >>= 1)
            t += __shfl_down(t, off);
        if (tid == 0)
            out[0] = -t * (1.0f / 16777216.0f);   // -sum / (B*n*n)
    }
}

extern "C" void kernel_launch(void* const* d_in, const int* in_sizes, int n_in,
                              void* d_out, int out_size, void* d_ws, size_t ws_size,
                              hipStream_t stream)
{
    const float* pred     = (const float*)d_in[0];
    const float* labels   = (const float*)d_in[1];
    const float* rank_ema = (const float*)d_in[2];
    float* out = (float*)d_out;

    float*        partial = (float*)d_ws;                       // 16 KiB
    unsigned int* counter = (unsigned int*)((char*)d_ws + NBLK * sizeof(float));

    // d_ws is re-poisoned 0xAA before every launch: zero the done-counter.
    // (hipMemsetAsync is graph-capture legal; the harness uses it itself.)
    hipMemsetAsync(counter, 0, sizeof(unsigned int), stream);

    diffsort_loss_kernel<<<NBLK, BLK, 0, stream>>>(pred, labels, rank_ema,
                                                   partial, counter, out);
}